// Round 1
// baseline (33.029 us; speedup 1.0000x reference)
//
#include <hip/hip_runtime.h>
#include <math.h>

#define BSZ 32
#define NPT 8192

// ws layout (floats):
// [0..31]    acc_sq   (sum of squared distances per b1)
// [32..63]   acc_rsq  (sum of sqrt distances per b1)
// [64..95]   re per b
// [96..127]  te per b
// [128..159] has_inlier per b (1.0/0.0)

__global__ void stats_kernel(const float* __restrict__ trans,
                             const float* __restrict__ gt_trans,
                             const float* __restrict__ probs,
                             float* __restrict__ ws) {
    int b = blockIdx.x;
    int tid = threadIdx.x;

    // has_inlier = any(probs[b,:] > 0)
    int found = 0;
    const float* p = probs + (size_t)b * NPT;
    for (int n = tid; n < NPT; n += blockDim.x) {
        if (p[n] > 0.0f) found = 1;
    }
    unsigned long long m = __ballot(found != 0);
    __shared__ int s_found[4];
    int wave = tid >> 6;
    if ((tid & 63) == 0) s_found[wave] = (m != 0ull) ? 1 : 0;
    __syncthreads();

    if (tid == 0) {
        int f = 0;
        int nwaves = (int)(blockDim.x >> 6);
        for (int w = 0; w < nwaves; ++w) f |= s_found[w];
        ws[128 + b] = f ? 1.0f : 0.0f;

        const float* T = trans + b * 16;
        const float* G = gt_trans + b * 16;
        float tr = 0.0f;
        #pragma unroll
        for (int i = 0; i < 3; ++i)
            #pragma unroll
            for (int j = 0; j < 3; ++j)
                tr += T[i * 4 + j] * G[i * 4 + j];
        float c = (tr - 1.0f) * 0.5f;
        c = fminf(1.0f, fmaxf(-1.0f, c));
        float re = acosf(c) * (180.0f / (float)M_PI);

        float dx = T[3] - G[3];
        float dy = T[7] - G[7];
        float dz = T[11] - G[11];
        float te = sqrtf(dx * dx + dy * dy + dz * dz) * 100.0f;

        ws[64 + b] = re;
        ws[96 + b] = te;
    }
}

__global__ __launch_bounds__(256) void pair_kernel(
    const float* __restrict__ trans,
    const float* __restrict__ src,
    const float* __restrict__ tgt,
    float* __restrict__ ws) {
    const int b1 = blockIdx.y;            // 0..31
    const int n = blockIdx.x * 256 + threadIdx.x;   // 0..8191
    const int tid = threadIdx.x;

    // R, t for b1 (uniform across block -> scalar regs)
    const float* T = trans + b1 * 16;
    const float r00 = T[0], r01 = T[1], r02 = T[2],  t0 = T[3];
    const float r10 = T[4], r11 = T[5], r12 = T[6],  t1 = T[7];
    const float r20 = T[8], r21 = T[9], r22 = T[10], t2 = T[11];

    const float* s = src + ((size_t)b1 * NPT + n) * 3;
    const float sx = s[0], sy = s[1], sz = s[2];
    const float wx = r00 * sx + r01 * sy + r02 * sz + t0;
    const float wy = r10 * sx + r11 * sy + r12 * sz + t1;
    const float wz = r20 * sx + r21 * sy + r22 * sz + t2;

    float acc_sq = 0.0f, acc_rsq = 0.0f;
    #pragma unroll
    for (int b2 = 0; b2 < BSZ; ++b2) {
        const float* g = tgt + ((size_t)b2 * NPT + n) * 3;
        const float dx = wx - g[0];
        const float dy = wy - g[1];
        const float dz = wz - g[2];
        const float sq = dx * dx + dy * dy + dz * dz;
        acc_sq += sq;
        acc_rsq += sqrtf(sq);
    }

    // reduce within wave (64 lanes)
    #pragma unroll
    for (int off = 32; off > 0; off >>= 1) {
        acc_sq  += __shfl_down(acc_sq, off);
        acc_rsq += __shfl_down(acc_rsq, off);
    }
    __shared__ float s_sq[4], s_rsq[4];
    if ((tid & 63) == 0) { s_sq[tid >> 6] = acc_sq; s_rsq[tid >> 6] = acc_rsq; }
    __syncthreads();
    if (tid == 0) {
        float bsum = s_sq[0] + s_sq[1] + s_sq[2] + s_sq[3];
        float brs  = s_rsq[0] + s_rsq[1] + s_rsq[2] + s_rsq[3];
        atomicAdd(&ws[b1], bsum);
        atomicAdd(&ws[32 + b1], brs);
    }
}

__global__ void final_kernel(const float* __restrict__ ws,
                             float* __restrict__ out) {
    const int tid = threadIdx.x;
    float loss_c = 0.0f, recall_c = 0.0f, re_c = 0.0f, te_c = 0.0f, rmse_c = 0.0f;
    if (tid < BSZ) {
        const float inv = 1.0f / ((float)BSZ * (float)NPT);
        const float asq  = ws[tid];
        const float arsq = ws[32 + tid];
        const float re   = ws[64 + tid];
        const float te   = ws[96 + tid];
        const float inl  = ws[128 + tid];
        const float loss_per = asq * inv;
        loss_c   = (inl > 0.5f) ? loss_per : 0.0f;
        recall_c = ((te < 30.0f) && (re < 15.0f)) ? 1.0f : 0.0f;
        re_c = re;
        te_c = te;
        rmse_c = arsq * inv;
    }
    #pragma unroll
    for (int off = 32; off > 0; off >>= 1) {
        loss_c   += __shfl_down(loss_c, off);
        recall_c += __shfl_down(recall_c, off);
        re_c     += __shfl_down(re_c, off);
        te_c     += __shfl_down(te_c, off);
        rmse_c   += __shfl_down(rmse_c, off);
    }
    if (tid == 0) {
        out[0] = loss_c / (float)BSZ;
        out[1] = recall_c * 100.0f / (float)BSZ;
        out[2] = re_c / (float)BSZ;
        out[3] = te_c / (float)BSZ;
        out[4] = rmse_c / (float)BSZ;
    }
}

extern "C" void kernel_launch(void* const* d_in, const int* in_sizes, int n_in,
                              void* d_out, int out_size, void* d_ws, size_t ws_size,
                              hipStream_t stream) {
    const float* trans    = (const float*)d_in[0];
    const float* gt_trans = (const float*)d_in[1];
    const float* src      = (const float*)d_in[2];
    const float* tgt      = (const float*)d_in[3];
    const float* probs    = (const float*)d_in[4];
    float* ws  = (float*)d_ws;
    float* out = (float*)d_out;

    // zero the 64 accumulator floats (harness does not re-poison between replays)
    hipMemsetAsync(d_ws, 0, 64 * sizeof(float), stream);

    stats_kernel<<<BSZ, 256, 0, stream>>>(trans, gt_trans, probs, ws);

    dim3 grid(NPT / 256, BSZ);
    pair_kernel<<<grid, 256, 0, stream>>>(trans, src, tgt, ws);

    final_kernel<<<1, 64, 0, stream>>>(ws, out);
}

// Round 2
// 17.869 us; speedup vs baseline: 1.8484x; 1.8484x over previous
//
#include <hip/hip_runtime.h>
#include <math.h>

#define BSZ 32
#define NPT 8192
#define XB  8          // x-blocks per b1
#define PPT 4          // points per thread (256 thr * 8 blk * 4 = 8192)

// ws layout (floats):
// [0   .. 255]  sq  partials  [b1*XB + xb]
// [256 .. 511]  rsq partials
// [512 .. 767]  inlier partials (0.0/1.0)
// All slots written unconditionally every call -> no zeroing needed.

__global__ __launch_bounds__(256) void fused_kernel(
    const float* __restrict__ trans,
    const float* __restrict__ src,
    const float* __restrict__ tgt,
    const float* __restrict__ probs,
    float* __restrict__ ws)
{
    const int b1  = blockIdx.y;
    const int xb  = blockIdx.x;
    const int tid = threadIdx.x;
    const int n0  = (xb * 256 + tid) * PPT;   // first of 4 points

    // R, t for b1 (block-uniform -> SGPRs)
    const float* T = trans + b1 * 16;
    const float r00 = T[0], r01 = T[1], r02 = T[2],  t0 = T[3];
    const float r10 = T[4], r11 = T[5], r12 = T[6],  t1 = T[7];
    const float r20 = T[8], r21 = T[9], r22 = T[10], t2 = T[11];

    // 4 points = 48B = 3 aligned float4 loads
    const float4* sp = (const float4*)(src + ((size_t)b1 * NPT + n0) * 3);
    const float4 sA = sp[0], sB = sp[1], sC = sp[2];
    const float px[4] = {sA.x, sA.w, sB.z, sC.y};
    const float py[4] = {sA.y, sB.x, sB.w, sC.z};
    const float pz[4] = {sA.z, sB.y, sC.x, sC.w};
    float wx[4], wy[4], wz[4];
    #pragma unroll
    for (int i = 0; i < 4; ++i) {
        wx[i] = r00 * px[i] + r01 * py[i] + r02 * pz[i] + t0;
        wy[i] = r10 * px[i] + r11 * py[i] + r12 * pz[i] + t1;
        wz[i] = r20 * px[i] + r21 * py[i] + r22 * pz[i] + t2;
    }

    float acc_sq = 0.0f, acc_rsq = 0.0f;
    #pragma unroll 4
    for (int b2 = 0; b2 < BSZ; ++b2) {
        const float4* gp = (const float4*)(tgt + ((size_t)b2 * NPT + n0) * 3);
        const float4 gA = gp[0], gB = gp[1], gC = gp[2];
        const float gx[4] = {gA.x, gA.w, gB.z, gC.y};
        const float gy[4] = {gA.y, gB.x, gB.w, gC.z};
        const float gz[4] = {gA.z, gB.y, gC.x, gC.w};
        #pragma unroll
        for (int i = 0; i < 4; ++i) {
            const float dx = wx[i] - gx[i];
            const float dy = wy[i] - gy[i];
            const float dz = wz[i] - gz[i];
            const float sq = dx * dx + dy * dy + dz * dz;
            acc_sq  += sq;
            acc_rsq += sqrtf(sq);
        }
    }

    // fused probs scan: this block covers probs[b1, n0 .. n0+3] per thread
    const float4 pv = *(const float4*)(probs + (size_t)b1 * NPT + n0);
    const int found = (pv.x > 0.0f) | (pv.y > 0.0f) | (pv.z > 0.0f) | (pv.w > 0.0f);

    // wave reduce (64 lanes)
    #pragma unroll
    for (int off = 32; off > 0; off >>= 1) {
        acc_sq  += __shfl_down(acc_sq, off);
        acc_rsq += __shfl_down(acc_rsq, off);
    }
    const unsigned long long m = __ballot(found);

    __shared__ float s_sq[4], s_rsq[4];
    __shared__ int   s_f[4];
    const int wv = tid >> 6;
    if ((tid & 63) == 0) { s_sq[wv] = acc_sq; s_rsq[wv] = acc_rsq; s_f[wv] = (m != 0ull); }
    __syncthreads();
    if (tid == 0) {
        const int slot = b1 * XB + xb;
        ws[slot]       = s_sq[0] + s_sq[1] + s_sq[2] + s_sq[3];
        ws[256 + slot] = s_rsq[0] + s_rsq[1] + s_rsq[2] + s_rsq[3];
        ws[512 + slot] = (s_f[0] | s_f[1] | s_f[2] | s_f[3]) ? 1.0f : 0.0f;
    }
}

__global__ void final_kernel(const float* __restrict__ ws,
                             const float* __restrict__ trans,
                             const float* __restrict__ gt_trans,
                             float* __restrict__ out) {
    const int tid = threadIdx.x;   // 64 threads
    float loss_c = 0.0f, recall_c = 0.0f, re_c = 0.0f, te_c = 0.0f, rmse_c = 0.0f;
    if (tid < BSZ) {
        float asq = 0.0f, arsq = 0.0f, inl = 0.0f;
        #pragma unroll
        for (int k = 0; k < XB; ++k) {
            asq  += ws[tid * XB + k];
            arsq += ws[256 + tid * XB + k];
            inl  += ws[512 + tid * XB + k];
        }
        const float* T = trans + tid * 16;
        const float* G = gt_trans + tid * 16;
        float tr = 0.0f;
        #pragma unroll
        for (int i = 0; i < 3; ++i)
            #pragma unroll
            for (int j = 0; j < 3; ++j)
                tr += T[i * 4 + j] * G[i * 4 + j];
        float c = (tr - 1.0f) * 0.5f;
        c = fminf(1.0f, fmaxf(-1.0f, c));
        const float re = acosf(c) * 57.29577951308232f;

        const float dx = T[3] - G[3];
        const float dy = T[7] - G[7];
        const float dz = T[11] - G[11];
        const float te = sqrtf(dx * dx + dy * dy + dz * dz) * 100.0f;

        const float inv = 1.0f / ((float)BSZ * (float)NPT);
        const float loss_per = asq * inv;
        loss_c   = (inl > 0.5f) ? loss_per : 0.0f;
        recall_c = ((te < 30.0f) && (re < 15.0f)) ? 1.0f : 0.0f;
        re_c   = re;
        te_c   = te;
        rmse_c = arsq * inv;
    }
    #pragma unroll
    for (int off = 32; off > 0; off >>= 1) {
        loss_c   += __shfl_down(loss_c, off);
        recall_c += __shfl_down(recall_c, off);
        re_c     += __shfl_down(re_c, off);
        te_c     += __shfl_down(te_c, off);
        rmse_c   += __shfl_down(rmse_c, off);
    }
    if (tid == 0) {
        out[0] = loss_c / (float)BSZ;
        out[1] = recall_c * 100.0f / (float)BSZ;
        out[2] = re_c / (float)BSZ;
        out[3] = te_c / (float)BSZ;
        out[4] = rmse_c / (float)BSZ;
    }
}

extern "C" void kernel_launch(void* const* d_in, const int* in_sizes, int n_in,
                              void* d_out, int out_size, void* d_ws, size_t ws_size,
                              hipStream_t stream) {
    const float* trans    = (const float*)d_in[0];
    const float* gt_trans = (const float*)d_in[1];
    const float* src      = (const float*)d_in[2];
    const float* tgt      = (const float*)d_in[3];
    const float* probs    = (const float*)d_in[4];
    float* ws  = (float*)d_ws;
    float* out = (float*)d_out;

    dim3 grid(XB, BSZ);
    fused_kernel<<<grid, 256, 0, stream>>>(trans, src, tgt, probs, ws);
    final_kernel<<<1, 64, 0, stream>>>(ws, trans, gt_trans, out);
}

// Round 4
// 12.751 us; speedup vs baseline: 2.5903x; 1.4014x over previous
//
#include <hip/hip_runtime.h>
#include <math.h>

#define BSZ 32
#define NPT 8192
#define XB  8          // x-blocks per b1
#define PPT 4          // points per thread (256 thr * 8 blk * 4 = 8192)
#define G   4          // b2-groups (each covers BSZ/G = 8 b2 values)
#define B2P (BSZ / G)  // b2 per group

// ws layout (floats):
// [0    .. 1023]  sq  partials  [(b1*XB + xb)*G + g]
// [1024 .. 2047]  rsq partials  [(b1*XB + xb)*G + g]
// [2048 .. 2303]  inlier partials [b1*XB + xb]   (written by g==0 blocks)
// All slots written unconditionally every call -> no zeroing needed.

__global__ __launch_bounds__(256) void fused_kernel(
    const float* __restrict__ trans,
    const float* __restrict__ src,
    const float* __restrict__ tgt,
    const float* __restrict__ probs,
    float* __restrict__ ws)
{
    const int xb  = blockIdx.x;
    const int b1  = blockIdx.y;
    const int g   = blockIdx.z;
    const int tid = threadIdx.x;
    const int n0  = (xb * 256 + tid) * PPT;   // first of 4 points

    // R, t for b1 (block-uniform -> SGPRs)
    const float* T = trans + b1 * 16;
    const float r00 = T[0], r01 = T[1], r02 = T[2],  t0 = T[3];
    const float r10 = T[4], r11 = T[5], r12 = T[6],  t1 = T[7];
    const float r20 = T[8], r21 = T[9], r22 = T[10], t2 = T[11];

    // 4 points = 48B = 3 aligned float4 loads
    const float4* sp = (const float4*)(src + ((size_t)b1 * NPT + n0) * 3);
    const float4 sA = sp[0], sB = sp[1], sC = sp[2];
    const float px[4] = {sA.x, sA.w, sB.z, sC.y};
    const float py[4] = {sA.y, sB.x, sB.w, sC.z};
    const float pz[4] = {sA.z, sB.y, sC.x, sC.w};
    float wx[4], wy[4], wz[4];
    #pragma unroll
    for (int i = 0; i < 4; ++i) {
        wx[i] = r00 * px[i] + r01 * py[i] + r02 * pz[i] + t0;
        wy[i] = r10 * px[i] + r11 * py[i] + r12 * pz[i] + t1;
        wz[i] = r20 * px[i] + r21 * py[i] + r22 * pz[i] + t2;
    }

    float acc_sq = 0.0f, acc_rsq = 0.0f;
    #pragma unroll
    for (int k = 0; k < B2P; ++k) {
        const int b2 = g * B2P + k;
        const float4* gp = (const float4*)(tgt + ((size_t)b2 * NPT + n0) * 3);
        const float4 gA = gp[0], gB = gp[1], gC = gp[2];
        const float gx[4] = {gA.x, gA.w, gB.z, gC.y};
        const float gy[4] = {gA.y, gB.x, gB.w, gC.z};
        const float gz[4] = {gA.z, gB.y, gC.x, gC.w};
        #pragma unroll
        for (int i = 0; i < 4; ++i) {
            const float dx = wx[i] - gx[i];
            const float dy = wy[i] - gy[i];
            const float dz = wz[i] - gz[i];
            const float sq = dx * dx + dy * dy + dz * dz;
            acc_sq  += sq;
            acc_rsq += __builtin_amdgcn_sqrtf(sq);
        }
    }

    // wave reduce (64 lanes)
    #pragma unroll
    for (int off = 32; off > 0; off >>= 1) {
        acc_sq  += __shfl_down(acc_sq, off);
        acc_rsq += __shfl_down(acc_rsq, off);
    }

    __shared__ float s_sq[4], s_rsq[4];
    __shared__ int   s_f[4];
    const int wv = tid >> 6;

    int anyf = 0;
    if (g == 0) {
        // fused probs scan (only one b2-group needs it)
        const float4 pv = *(const float4*)(probs + (size_t)b1 * NPT + n0);
        const int found = (pv.x > 0.0f) | (pv.y > 0.0f) | (pv.z > 0.0f) | (pv.w > 0.0f);
        anyf = (__ballot(found) != 0ull);
    }

    if ((tid & 63) == 0) { s_sq[wv] = acc_sq; s_rsq[wv] = acc_rsq; s_f[wv] = anyf; }
    __syncthreads();
    if (tid == 0) {
        const int slot = (b1 * XB + xb) * G + g;
        ws[slot]        = s_sq[0] + s_sq[1] + s_sq[2] + s_sq[3];
        ws[1024 + slot] = s_rsq[0] + s_rsq[1] + s_rsq[2] + s_rsq[3];
        if (g == 0)
            ws[2048 + b1 * XB + xb] = (s_f[0] | s_f[1] | s_f[2] | s_f[3]) ? 1.0f : 0.0f;
    }
}

__global__ void final_kernel(const float* __restrict__ ws,
                             const float* __restrict__ trans,
                             const float* __restrict__ gt_trans,
                             float* __restrict__ out) {
    const int tid = threadIdx.x;   // 64 threads
    float loss_c = 0.0f, recall_c = 0.0f, re_c = 0.0f, te_c = 0.0f, rmse_c = 0.0f;
    if (tid < BSZ) {
        float asq = 0.0f, arsq = 0.0f, inl = 0.0f;
        #pragma unroll
        for (int k = 0; k < XB * G; ++k) {
            asq  += ws[tid * XB * G + k];
            arsq += ws[1024 + tid * XB * G + k];
        }
        #pragma unroll
        for (int k = 0; k < XB; ++k) inl += ws[2048 + tid * XB + k];

        const float* T = trans + tid * 16;
        const float* Gt = gt_trans + tid * 16;
        float tr = 0.0f;
        #pragma unroll
        for (int i = 0; i < 3; ++i)
            #pragma unroll
            for (int j = 0; j < 3; ++j)
                tr += T[i * 4 + j] * Gt[i * 4 + j];
        float c = (tr - 1.0f) * 0.5f;
        c = fminf(1.0f, fmaxf(-1.0f, c));
        const float re = acosf(c) * 57.29577951308232f;

        const float dx = T[3] - Gt[3];
        const float dy = T[7] - Gt[7];
        const float dz = T[11] - Gt[11];
        const float te = sqrtf(dx * dx + dy * dy + dz * dz) * 100.0f;

        const float inv = 1.0f / ((float)BSZ * (float)NPT);
        const float loss_per = asq * inv;
        loss_c   = (inl > 0.5f) ? loss_per : 0.0f;
        recall_c = ((te < 30.0f) && (re < 15.0f)) ? 1.0f : 0.0f;
        re_c   = re;
        te_c   = te;
        rmse_c = arsq * inv;
    }
    #pragma unroll
    for (int off = 32; off > 0; off >>= 1) {
        loss_c   += __shfl_down(loss_c, off);
        recall_c += __shfl_down(recall_c, off);
        re_c     += __shfl_down(re_c, off);
        te_c     += __shfl_down(te_c, off);
        rmse_c   += __shfl_down(rmse_c, off);
    }
    if (tid == 0) {
        out[0] = loss_c / (float)BSZ;
        out[1] = recall_c * 100.0f / (float)BSZ;
        out[2] = re_c / (float)BSZ;
        out[3] = te_c / (float)BSZ;
        out[4] = rmse_c / (float)BSZ;
    }
}

extern "C" void kernel_launch(void* const* d_in, const int* in_sizes, int n_in,
                              void* d_out, int out_size, void* d_ws, size_t ws_size,
                              hipStream_t stream) {
    const float* trans    = (const float*)d_in[0];
    const float* gt_trans = (const float*)d_in[1];
    const float* src      = (const float*)d_in[2];
    const float* tgt      = (const float*)d_in[3];
    const float* probs    = (const float*)d_in[4];
    float* ws  = (float*)d_ws;
    float* out = (float*)d_out;

    dim3 grid(XB, BSZ, G);
    fused_kernel<<<grid, 256, 0, stream>>>(trans, src, tgt, probs, ws);
    final_kernel<<<1, 64, 0, stream>>>(ws, trans, gt_trans, out);
}